// Round 3
// baseline (8911.835 us; speedup 1.0000x reference)
//
#include <hip/hip_runtime.h>
#include <stdint.h>
#include <stddef.h>

typedef __attribute__((ext_vector_type(8))) _Float16 half8;
typedef __attribute__((ext_vector_type(8))) unsigned short ushort8;
typedef __attribute__((ext_vector_type(4))) float f4;

namespace {
constexpr int kSteps = 255;   // reference iterates t = 0 .. T-2
constexpr int KTOT = 1152;    // 1024 (h) + 128 (x)

// workspace layout (bytes); total ~45 MB
constexpr size_t OFF_H0   = 0;                                   // 1 MB  h ping
constexpr size_t OFF_CNT  = (size_t)1 << 20;                     // 4 KB  barrier counters (4 groups, 64B apart)
constexpr size_t OFF_H1   = ((size_t)1 << 20) + 4096;            // 1 MB  h pong
constexpr size_t OFF_BSUM = OFF_H1 + ((size_t)1 << 20);          // 16 KB b_ih+b_hh (fp32)
constexpr size_t OFF_WCAT = OFF_BSUM + 16384;                    // 9.4 MB fp16 [4096][1152] = [W_hh | W_ih]
constexpr size_t OFF_XT   = OFF_WCAT + (size_t)4096 * KTOT * 2;  // 33.4 MB fp16 [255][512][128]
}

__device__ __forceinline__ unsigned short f2h(float f) {   // RNE float->fp16
  _Float16 h = (_Float16)f;
  return __builtin_bit_cast(unsigned short, h);
}
__device__ __forceinline__ float h2f(unsigned short s) {
  return (float)__builtin_bit_cast(_Float16, s);
}

// ---------- prep 1: Wcat fp16 + bsum ----------
__global__ void prep_wcat(const float* __restrict__ Wih, const float* __restrict__ Whh,
                          const float* __restrict__ bih, const float* __restrict__ bhh,
                          char* __restrict__ ws) {
  if (blockIdx.x < 2304) {                       // 2304*256 = 4096*144 8-elem chunks
    unsigned gid = blockIdx.x * 256 + threadIdx.x;
    unsigned row = gid / 144, cc = gid % 144;
    const float* src = (cc < 128) ? (Whh + (size_t)row * 1024 + (size_t)cc * 8)
                                  : (Wih + (size_t)row * 128 + (size_t)(cc - 128) * 8);
    ushort8 o;
#pragma unroll
    for (int j = 0; j < 8; j++) o[j] = f2h(src[j]);
    *(ushort8*)((unsigned short*)(ws + OFF_WCAT) + (size_t)row * KTOT + cc * 8) = o;
  } else {
    int i = (blockIdx.x - 2304) * 256 + threadIdx.x;   // 16 blocks -> 4096
    ((float*)(ws + OFF_BSUM))[i] = bih[i] + bhh[i];
  }
}

// ---------- prep 2: xT[t][b][i] = fp16(x[b][i][t]), t < 255 (LDS tile transpose) ----------
__global__ void prep_xt(const float* __restrict__ x, char* __restrict__ ws) {
  unsigned short* xT = (unsigned short*)(ws + OFF_XT);
  __shared__ unsigned short tile[128][72];     // +pad vs 64 to break bank alias
  const int b = blockIdx.x >> 2;
  const int t0 = (blockIdx.x & 3) * 64;
  const int wv = threadIdx.x >> 6, tl = threadIdx.x & 63;
  if (t0 + tl < 255) {
#pragma unroll
    for (int ii = 0; ii < 32; ii++) {
      int i = wv + ii * 4;
      tile[i][tl] = f2h(x[((size_t)b * 128 + i) * 256 + t0 + tl]);   // coalesced over t
    }
  }
  __syncthreads();
  const int tl2 = threadIdx.x >> 4, ic = threadIdx.x & 15;
#pragma unroll
  for (int pp = 0; pp < 4; pp++) {
    int tloc = pp * 16 + tl2;
    int t = t0 + tloc;
    if (t < 255) {
      ushort8 v;
#pragma unroll
      for (int j = 0; j < 8; j++) v[j] = tile[ic * 8 + j][tloc];
      *(ushort8*)&xT[((size_t)t * 512 + b) * 128 + ic * 8] = v;      // 16B coalesced per t
    }
  }
}

// ---------- persistent LSTM kernel ----------
// grid 256 = 4 batch-groups (128 rows) x 64 unit-groups (16 units). 8 waves = 2M x 2N x 2K.
// Wave tile: M=64 rows, N=32 gate cols, K split even/odd 64-col chunks (B-frags in 144 VGPRs).
__global__ __launch_bounds__(512, 2) void lstm_persist(char* __restrict__ ws) {
  const unsigned short* __restrict__ wcat = (const unsigned short*)(ws + OFF_WCAT);
  const float* __restrict__ bsum = (const float*)(ws + OFF_BSUM);
  const unsigned short* __restrict__ xT = (const unsigned short*)(ws + OFF_XT);
  unsigned short* h0 = (unsigned short*)(ws + OFF_H0);
  unsigned short* h1 = (unsigned short*)(ws + OFF_H1);

  __shared__ unsigned short Ab[4][8192];   // 4 x 16KB A-staging (bufs 0,1 reused as reduce scratch)

  const int tid = threadIdx.x;
  const int lane = tid & 63;
  const int w = tid >> 6;
  const int wk = w & 1;           // K parity (even/odd chunks)
  const int wm = (w >> 1) & 1;    // M half
  const int wn = (w >> 2) & 1;    // N half
  const int l15 = lane & 15, l4 = lane >> 4, g = lane & 3, p = lane & 3;
  const int gblk = blockIdx.x >> 6;
  const int cblk = blockIdx.x & 63;
  const int B0 = gblk * 128;      // batch rows
  const int U0 = cblk * 16;       // hidden units
  int* cntp = (int*)(ws + OFF_CNT) + gblk * 16;   // one counter per group, 64B apart

  // ---- weight fragments -> registers (persist whole kernel). col c -> unit c>>2, gate c&3 ----
  half8 bf[18][2];
  float bs[2];
#pragma unroll
  for (int nf = 0; nf < 2; nf++) {
    int u = wn * 8 + nf * 4 + (l15 >> 2);
    int R = g * 1024 + U0 + u;                  // PyTorch gate order i,f,g,o in 1024-chunks
    bs[nf] = bsum[R];
#pragma unroll
    for (int j = 0; j < 9; j++)
#pragma unroll
      for (int s = 0; s < 2; s++) {
        int gk = ((2 * j + wk) * 2 + s) * 32 + l4 * 8;
        bf[j * 2 + s][nf] = *(const half8*)&wcat[(size_t)R * KTOT + gk];
      }
  }
  // K-reduction sums two wave-halves that BOTH init acc; only wk==0 seeds the bias.
  const float bseed0 = (wk == 0) ? bs[0] : 0.f;
  const float bseed1 = (wk == 0) ? bs[1] : 0.f;

  // ---- staging slot constants (4 global_load_lds per wave per chunk-pair) ----
  // LDS 16B-slot s within a 16KB chunk holds (row = s>>3, col-chunk c8 = (s&7)^(row&7)): linear
  // dest + inverse-swizzled source; ds_read applies the same XOR -> conflict-free.
  int subIdx[4], cHalf[4], hofs[4], xofs[4];
#pragma unroll
  for (int i = 0; i < 4; i++) {
    int slot = w * 4 + i;
    int ph = slot >> 4, sub = slot & 15;
    int s = sub * 64 + lane;
    int row = s >> 3;
    int c8 = (s & 7) ^ (row & 7);
    subIdx[i] = sub; cHalf[i] = ph;
    hofs[i] = (B0 + row) * 1024 + c8 * 8;
    xofs[i] = (B0 + row) * 128 + c8 * 8;
  }
  int aofs[4][2];
#pragma unroll
  for (int m = 0; m < 4; m++)
#pragma unroll
    for (int s = 0; s < 2; s++) {
      int rowl = wm * 64 + m * 16 + l15;
      int c8r = s * 4 + l4;
      aofs[m][s] = rowl * 128 + ((c8r ^ (rowl & 7)) * 16);
    }

  f4 acc[4][2];

  auto STAGE = [&](int jn, bool isX, const unsigned short* hsrc, const unsigned short* xslab) {
#pragma unroll
    for (int i = 0; i < 4; i++) {
      int c = 2 * jn + cHalf[i];
      int bufidx = (jn & 1) * 2 + cHalf[i];
      const unsigned short* src = isX ? (xslab + xofs[i] + (c - 16) * 64)
                                      : (hsrc + hofs[i] + c * 64);
      __builtin_amdgcn_global_load_lds(
          (const __attribute__((address_space(1))) void*)src,
          (__attribute__((address_space(3))) void*)&Ab[bufidx][subIdx[i] * 512],
          16, 0, 0);
    }
  };
  auto COMPUTE = [&](int jn) {
    int bufidx = (jn & 1) * 2 + wk;
    const char* base = (const char*)&Ab[bufidx][0];
#pragma unroll
    for (int s = 0; s < 2; s++) {
      half8 a[4];
#pragma unroll
      for (int m = 0; m < 4; m++) a[m] = *(const half8*)(base + aofs[m][s]);
#pragma unroll
      for (int m = 0; m < 4; m++)
#pragma unroll
        for (int nf = 0; nf < 2; nf++)
          acc[m][nf] = __builtin_amdgcn_mfma_f32_16x16x32_f16(a[m], bf[jn * 2 + s][nf],
                                                              acc[m][nf], 0, 0, 0);
    }
  };

  float creg[2][2] = {{0.f, 0.f}, {0.f, 0.f}};   // c state lives in registers forever

#pragma unroll 1
  for (int t = 0; t < kSteps; t++) {
    const unsigned short* hsrc = (t & 1) ? h1 : h0;
    unsigned short* hdst = (t & 1) ? h0 : h1;
    const unsigned short* xslab = xT + (size_t)t * (512 * 128);

#pragma unroll
    for (int m = 0; m < 4; m++) {
      acc[m][0] = (f4){bseed0, bseed0, bseed0, bseed0};
      acc[m][1] = (f4){bseed1, bseed1, bseed1, bseed1};
    }

    // x-contribution (chunks 16,17) needs no barrier -> hides part of the rendezvous
    STAGE(8, true, hsrc, xslab);
    __syncthreads();
    COMPUTE(8);

    if (tid == 0) {              // wait: all 64 blocks of this group finished step t-1
      int target = 64 * t;
      int guard = 1 << 18;       // bounded spin: never hang the harness
      while (__hip_atomic_load(cntp, __ATOMIC_ACQUIRE, __HIP_MEMORY_SCOPE_AGENT) < target &&
             --guard) __builtin_amdgcn_s_sleep(1);
    }
    __syncthreads();

    STAGE(0, false, hsrc, xslab);
    __syncthreads();
#pragma unroll
    for (int j = 0; j < 8; j++) {
      if (j < 7) STAGE(j + 1, false, hsrc, xslab);
      COMPUTE(j);
      __syncthreads();           // stage j+1 landed; buffers of j-1 free
    }

    // ---- cross-wave K reduction through LDS (first 32KB of Ab) ----
    float* red = (float*)&Ab[0][0];
    {
      const int myoff = w * 1024 + lane * 4;
#pragma unroll
      for (int mi = 0; mi < 2; mi++)
#pragma unroll
        for (int nf = 0; nf < 2; nf++) {
          f4 v = wk ? acc[mi][nf] : acc[2 + mi][nf];       // partner's m-half
          *(f4*)&red[myoff + (mi * 2 + nf) * 256] = v;
        }
    }
    __syncthreads();
    {
      const int proff = (w ^ 1) * 1024 + lane * 4;
#pragma unroll
      for (int mi = 0; mi < 2; mi++)
#pragma unroll
        for (int nf = 0; nf < 2; nf++) {
          f4 mine = wk ? acc[2 + mi][nf] : acc[mi][nf];    // my kept m-half
          f4 oth = *(const f4*)&red[proff + (mi * 2 + nf) * 256];
          f4 gs = mine + oth;
          // activation: lane's gate type g (i,f,o -> sigmoid; g==2 -> tanh = 2*sig(2x)-1)
          float sc = (g == 2) ? 2.f : 1.f;
          float aa = (g == 2) ? 2.f : 1.f;
          float ab = (g == 2) ? -1.f : 0.f;
          float a0 = aa / (1.f + __expf(-sc * gs[0])) + ab;
          float a1 = aa / (1.f + __expf(-sc * gs[1])) + ab;
          float a2 = aa / (1.f + __expf(-sc * gs[2])) + ab;
          float a3 = aa / (1.f + __expf(-sc * gs[3])) + ab;
          // 4x4 transpose within lane quad: lane p ends with (i,f,g~,o) for batch j=p
          float s0 = (p & 1) ? a0 : a1;
          float s1 = (p & 1) ? a2 : a3;
          s0 = __shfl_xor(s0, 1); s1 = __shfl_xor(s1, 1);
          float A0 = (p & 1) ? s0 : a0;
          float A1 = (p & 1) ? a1 : s0;
          float A2 = (p & 1) ? s1 : a2;
          float A3 = (p & 1) ? a3 : s1;
          float t0 = (p & 2) ? A0 : A2;
          float t1 = (p & 2) ? A1 : A3;
          t0 = __shfl_xor(t0, 2); t1 = __shfl_xor(t1, 2);
          float q0 = (p & 2) ? t0 : A0;   // i
          float q1 = (p & 2) ? t1 : A1;   // f
          float q2 = (p & 2) ? A2 : t0;   // g~
          float q3 = (p & 2) ? A3 : t1;   // o
          float cn = q1 * creg[mi][nf] + q0 * q2;
          creg[mi][nf] = cn;
          float th = 2.f / (1.f + __expf(-2.f * cn)) - 1.f;
          float hv = q3 * th;
          int m = wk * 2 + mi;
          int rowg = B0 + wm * 64 + m * 16 + l4 * 4 + p;
          int col = U0 + wn * 8 + nf * 4 + ((lane >> 2) & 3);
          hdst[(size_t)rowg * 1024 + col] = f2h(hv);
        }
    }
    __syncthreads();             // drains h stores (vmcnt 0) before arrival
    if (tid == 0)
      __hip_atomic_fetch_add(cntp, 1, __ATOMIC_RELEASE, __HIP_MEMORY_SCOPE_AGENT);
  }
}

// ---------- FC: out = h_last @ W_fc^T + b_fc (fp32) ----------
__global__ void fc_kernel(const char* __restrict__ ws, const float* __restrict__ Wfc,
                          const float* __restrict__ bfc, float* __restrict__ out) {
  const unsigned short* h = (const unsigned short*)(ws + OFF_H1);  // buf[(254+1)&1] = h1
  int o = threadIdx.x & 127;
  int b = blockIdx.x * 2 + (threadIdx.x >> 7);
  const unsigned short* hrow = h + (size_t)b * 1024;
  const float* wrow = Wfc + (size_t)o * 1024;
  float acc = bfc[o];
#pragma unroll 4
  for (int k = 0; k < 1024; k += 8) {
    ushort8 hv = *(const ushort8*)&hrow[k];
    f4 w0 = *(const f4*)&wrow[k];
    f4 w1 = *(const f4*)&wrow[k + 4];
#pragma unroll
    for (int j = 0; j < 4; j++) acc += h2f(hv[j]) * w0[j];
#pragma unroll
    for (int j = 0; j < 4; j++) acc += h2f(hv[4 + j]) * w1[j];
  }
  out[(size_t)b * 128 + o] = acc;
}

extern "C" void kernel_launch(void* const* d_in, const int* in_sizes, int n_in,
                              void* d_out, int out_size, void* d_ws, size_t ws_size,
                              hipStream_t stream) {
  const float* x   = (const float*)d_in[0];
  const float* Wih = (const float*)d_in[1];
  const float* Whh = (const float*)d_in[2];
  const float* bih = (const float*)d_in[3];
  const float* bhh = (const float*)d_in[4];
  const float* Wfc = (const float*)d_in[5];
  const float* bfc = (const float*)d_in[6];
  char* ws = (char*)d_ws;

  // zero h0 + barrier counters every call (harness poisons ws once, never re-poisons)
  hipMemsetAsync(ws + OFF_H0, 0, ((size_t)1 << 20) + 4096, stream);
  prep_wcat<<<2320, 256, 0, stream>>>(Wih, Whh, bih, bhh, ws);
  prep_xt<<<2048, 256, 0, stream>>>(x, ws);
  lstm_persist<<<256, 512, 0, stream>>>(ws);
  fc_kernel<<<256, 256, 0, stream>>>(ws, Wfc, bfc, (float*)d_out);
}